// Round 11
// baseline (161.159 us; speedup 1.0000x reference)
//
#include <hip/hip_runtime.h>
#include <math.h>

typedef short bf16x2 __attribute__((ext_vector_type(2)));
typedef short bf16x4 __attribute__((ext_vector_type(4)));
typedef short bf16x8 __attribute__((ext_vector_type(8)));
typedef float f32x4 __attribute__((ext_vector_type(4)));

#define EMBED 1024
#define HEAD 128
#define BATCH 8
#define SEQ 2048

__device__ __forceinline__ short f2bf(float f) {
  union { float f; unsigned u; } v;
  v.f = f;
  unsigned r = v.u + 0x7fffu + ((v.u >> 16) & 1u);
  return (short)(r >> 16);
}

__device__ __forceinline__ void async_copy16(const void* g, void* l) {
#if __has_builtin(__builtin_amdgcn_global_load_lds)
  __builtin_amdgcn_global_load_lds(
      (const __attribute__((address_space(1))) unsigned int*)g,
      (__attribute__((address_space(3))) unsigned int*)l, 16, 0, 0);
#else
  *(f32x4*)l = *(const f32x4*)g;
#endif
}

// ---------------------------------------------------------------------------
// Kernel 0: weights fp32 [1024][128] -> WT3 chunk-linear image:
// WT3[(k>>3)*3072 + n*8 + (k&7)], n = mtx*128 + h (q|k|v). Wq * log2e/32.
// ---------------------------------------------------------------------------
__global__ __launch_bounds__(384) void wtrans_kernel(
    const float* __restrict__ Wq, const float* __restrict__ Wk,
    const float* __restrict__ Wv, short* __restrict__ WT3) {
  int kc8 = blockIdx.x;   // 0..127: chunk of 8 consecutive k
  int n = threadIdx.x;    // 0..383
  int mtx = n >> 7, h = n & 127;
  const float* W = (mtx == 0) ? Wq : ((mtx == 1) ? Wk : Wv);
  float scale = (mtx == 0) ? (1.4426950408889634f / 32.0f) : 1.0f;
  bf16x8 o;
#pragma unroll
  for (int j = 0; j < 8; j++)
    o[j] = f2bf(W[(size_t)(kc8 * 8 + j) * HEAD + h] * scale);
  *(bf16x8*)&WT3[(size_t)kc8 * 3072 + n * 8] = o;
}

// ---------------------------------------------------------------------------
// Kernel 1: FUSED QKV projection, THREE barrier domains per CU (extending
// R8's confirmed 1->2 domain win). Block = 64 rows x 128 cols, 4 waves of
// 64m x 32n (acc[4][2]), BK=64, register-B double-banked (4 frags/bank),
// grid 768 = 256 mt x 3 nh; mt = bx&255 keeps all 3 nh-siblings on one XCD
// (x-tile L2-shared; HBM x-traffic stays 64 MB; B reads stay 196 MB since
// each block reads its own cols exactly once). LDS 3x18.4 KB = 55 KB ->
// 3 blocks/CU. Per-CU MFMA/iter unchanged (3x4x16 = 192). Raw lgkmcnt-only
// barrier (no gload_lds here).
// ---------------------------------------------------------------------------
#define MFMA_BF16(D, A, B) D = __builtin_amdgcn_mfma_f32_16x16x32_bf16(A, B, D, 0, 0, 0)

#define PROJ_BARRIER() asm volatile("s_waitcnt lgkmcnt(0)\n\ts_barrier" ::: "memory")

#define PROJ_BODY(IT, C0, C1, C2, C3, N0, N1, N2, N3)                          \
  {                                                                            \
    int it_ = (IT);                                                            \
    PROJ_BARRIER();                                                            \
    if (it_ < 15) {                                                            \
      const short* bp_ = bptr + (it_ + 1) * 24576;                             \
      N0 = *(const bf16x8*)(bp_);                                              \
      N1 = *(const bf16x8*)(bp_ + 128);                                        \
      N2 = *(const bf16x8*)(bp_ + 12288);                                      \
      N3 = *(const bf16x8*)(bp_ + 12288 + 128);                                \
      bf16x8 w0_, w1_;                                                         \
      w0_[0] = f2bf(xr0[0]); w0_[1] = f2bf(xr0[1]);                            \
      w0_[2] = f2bf(xr0[2]); w0_[3] = f2bf(xr0[3]);                            \
      w0_[4] = f2bf(xr1[0]); w0_[5] = f2bf(xr1[1]);                            \
      w0_[6] = f2bf(xr1[2]); w0_[7] = f2bf(xr1[3]);                            \
      w1_[0] = f2bf(xr2[0]); w1_[1] = f2bf(xr2[1]);                            \
      w1_[2] = f2bf(xr2[2]); w1_[3] = f2bf(xr2[3]);                            \
      w1_[4] = f2bf(xr3[0]); w1_[5] = f2bf(xr3[1]);                            \
      w1_[6] = f2bf(xr3[2]); w1_[7] = f2bf(xr3[3]);                            \
      *(bf16x8*)&As[(it_ & 1) ^ 1][aoff] = w0_;                                \
      *(bf16x8*)&As[(it_ & 1) ^ 1][aoff + 8] = w1_;                            \
      if (it_ < 14) {                                                          \
        const float* xp_ = xbase + (it_ + 2) * 64;                             \
        xr0 = *(const f32x4*)(xp_);                                            \
        xr1 = *(const f32x4*)(xp_ + 4);                                        \
        xr2 = *(const f32x4*)(xp_ + 8);                                        \
        xr3 = *(const f32x4*)(xp_ + 12);                                       \
      }                                                                        \
    }                                                                          \
    {                                                                          \
      const short* as_ = &As[it_ & 1][0];                                      \
      bf16x8 a0_ = *(const bf16x8*)&as_[sub * 72 + quad * 8];                  \
      bf16x8 a1_ = *(const bf16x8*)&as_[(16 + sub) * 72 + quad * 8];           \
      bf16x8 a2_ = *(const bf16x8*)&as_[(32 + sub) * 72 + quad * 8];           \
      bf16x8 a3_ = *(const bf16x8*)&as_[(48 + sub) * 72 + quad * 8];           \
      MFMA_BF16(acc[0][0], a0_, C0); MFMA_BF16(acc[1][0], a1_, C0);            \
      MFMA_BF16(acc[2][0], a2_, C0); MFMA_BF16(acc[3][0], a3_, C0);            \
      MFMA_BF16(acc[0][1], a0_, C1); MFMA_BF16(acc[1][1], a1_, C1);            \
      MFMA_BF16(acc[2][1], a2_, C1); MFMA_BF16(acc[3][1], a3_, C1);            \
      a0_ = *(const bf16x8*)&as_[sub * 72 + 32 + quad * 8];                    \
      a1_ = *(const bf16x8*)&as_[(16 + sub) * 72 + 32 + quad * 8];             \
      a2_ = *(const bf16x8*)&as_[(32 + sub) * 72 + 32 + quad * 8];             \
      a3_ = *(const bf16x8*)&as_[(48 + sub) * 72 + 32 + quad * 8];             \
      MFMA_BF16(acc[0][0], a0_, C2); MFMA_BF16(acc[1][0], a1_, C2);            \
      MFMA_BF16(acc[2][0], a2_, C2); MFMA_BF16(acc[3][0], a3_, C2);            \
      MFMA_BF16(acc[0][1], a0_, C3); MFMA_BF16(acc[1][1], a1_, C3);            \
      MFMA_BF16(acc[2][1], a2_, C3); MFMA_BF16(acc[3][1], a3_, C3);            \
    }                                                                          \
  }

__global__ __launch_bounds__(256, 3) void proj_kernel(
    const float* __restrict__ x, const short* __restrict__ WT3,
    short* __restrict__ q, short* __restrict__ kG, short* __restrict__ vG) {
  __shared__ __align__(16) short As[2][64 * 72];   // 18.4 KiB, stride 144B
  int tid = threadIdx.x;
  int w = tid >> 6, lane = tid & 63, quad = lane >> 4, sub = lane & 15;
  int bx = blockIdx.x;
  int mt = bx & 255;          // all 3 nh of a tile: same XCD (256%8==0)
  int nh = bx >> 8;           // n-third: cols nh*128 .. +128
  int m0 = mt * 64;

  // A staging: thread covers row (tid>>2), 16 k-floats at (tid&3)*16
  int arow = tid >> 2;
  int akq = (tid & 3) * 16;
  const float* xbase = x + (size_t)(m0 + arow) * EMBED + akq;
  int aoff = arow * 72 + akq;

  // per-lane B base: frag(ks,an) at bptr + it*24576 + ks*12288 + an*128
  const short* bptr = WT3 + quad * 3072 + (nh * 128 + w * 32 + sub) * 8;

  f32x4 acc[4][2];
#pragma unroll
  for (int am = 0; am < 4; am++)
#pragma unroll
    for (int an = 0; an < 2; an++) acc[am][an] = (f32x4)(0.0f);

  // prologue: stage A iter 0, prefetch xr for iter 1, load B bank for iter 0
  {
    f32x4 x0 = *(const f32x4*)(xbase + 0);
    f32x4 x1 = *(const f32x4*)(xbase + 4);
    f32x4 x2 = *(const f32x4*)(xbase + 8);
    f32x4 x3 = *(const f32x4*)(xbase + 12);
    bf16x8 w0, w1;
    w0[0]=f2bf(x0[0]); w0[1]=f2bf(x0[1]); w0[2]=f2bf(x0[2]); w0[3]=f2bf(x0[3]);
    w0[4]=f2bf(x1[0]); w0[5]=f2bf(x1[1]); w0[6]=f2bf(x1[2]); w0[7]=f2bf(x1[3]);
    w1[0]=f2bf(x2[0]); w1[1]=f2bf(x2[1]); w1[2]=f2bf(x2[2]); w1[3]=f2bf(x2[3]);
    w1[4]=f2bf(x3[0]); w1[5]=f2bf(x3[1]); w1[6]=f2bf(x3[2]); w1[7]=f2bf(x3[3]);
    *(bf16x8*)&As[0][aoff] = w0;
    *(bf16x8*)&As[0][aoff + 8] = w1;
  }
  f32x4 xr0 = *(const f32x4*)(xbase + 64);
  f32x4 xr1 = *(const f32x4*)(xbase + 68);
  f32x4 xr2 = *(const f32x4*)(xbase + 72);
  f32x4 xr3 = *(const f32x4*)(xbase + 76);
  bf16x8 bA0, bA1, bA2, bA3;
  bf16x8 bB0, bB1, bB2, bB3;
  bA0 = *(const bf16x8*)(bptr);
  bA1 = *(const bf16x8*)(bptr + 128);
  bA2 = *(const bf16x8*)(bptr + 12288);
  bA3 = *(const bf16x8*)(bptr + 12288 + 128);

  for (int it2 = 0; it2 < 16; it2 += 2) {
    PROJ_BODY(it2,     bA0, bA1, bA2, bA3, bB0, bB1, bB2, bB3);
    PROJ_BODY(it2 + 1, bB0, bB1, bB2, bB3, bA0, bA1, bA2, bA3);
  }

  // epilogue: global frag group G = nh*8 + w*2 + an (16 cols each,
  // 8 per matrix); wave-uniform branch (nh,w uniform, an unrolled).
#pragma unroll
  for (int am = 0; am < 4; am++)
#pragma unroll
    for (int an = 0; an < 2; an++) {
      int g = nh * 8 + w * 2 + an;
      int hcol = (g & 7) * 16 + sub;
      if (g < 8) {                // q: row-major [t][h]
#pragma unroll
        for (int r = 0; r < 4; r++) {
          int m = m0 + am * 16 + quad * 4 + r;
          q[(size_t)m * HEAD + hcol] = f2bf(acc[am][an][r]);
        }
      } else if (g < 16) {        // kG: [t32][h>>3][t&31][h&7]
        size_t base = (size_t)(mt * 2 + (am >> 1)) * 4096 + (hcol >> 3) * 256 + (hcol & 7);
#pragma unroll
        for (int r = 0; r < 4; r++)
          kG[base + ((am & 1) * 16 + quad * 4 + r) * 8] = f2bf(acc[am][an][r]);
      } else {                    // vG: [t32][(t&31)>>3][h][t&7]
        bf16x4 pv;
#pragma unroll
        for (int r = 0; r < 4; r++) pv[r] = f2bf(acc[am][an][r]);
        *(bf16x4*)&vG[(size_t)(mt * 2 + (am >> 1)) * 4096 +
                      ((am & 1) * 2 + (quad >> 1)) * 1024 +
                      hcol * 8 + (quad & 1) * 4] = pv;
      }
    }
}

// ---------------------------------------------------------------------------
// Kernel 2: causal attention flash (R9 structure, reverted from R10's
// 128-row tiles which were neutral-negative: 64-row q-tiles, 4 waves,
// double-buffered K/V via linear gload_lds from pre-chunked kG/vG,
// __syncthreads per 32-key tile, Pb single-buffered -> 37 KB -> 4 blocks/CU).
// ---------------------------------------------------------------------------
__global__ __launch_bounds__(256, 4) void attn_kernel(
    const short* __restrict__ q, const short* __restrict__ kG,
    const short* __restrict__ vG, float* __restrict__ o_acc,
    float* __restrict__ l_acc) {
  __shared__ __align__(16) short Kb[2][4096];   // [hc 0..15][key 0..31] chunks
  __shared__ __align__(16) short Vb[2][4096];   // [kc 0..3][h 0..127] chunks
  __shared__ __align__(16) short Pb[4][16 * 40];
  int tid = threadIdx.x;
  int w = tid >> 6, lane = tid & 63, quad = lane >> 4, sub = lane & 15;
  int bx = blockIdx.x;
  int b = bx & 7;           // batch <-> XCD affinity (K/V L2-resident)
  int v = 79 - (bx >> 3);   // heavy chunks dispatched first
  int qt, c;
  if (v < 8)       { qt = v;                               c = 0; }
  else if (v < 24) { int i2 = v - 8;  qt = 8  + (i2 >> 1); c = i2 & 1; }
  else if (v < 48) { int i2 = v - 24; qt = 16 + i2 / 3;    c = i2 % 3; }
  else             { int i2 = v - 48; qt = 24 + (i2 >> 2); c = i2 & 3; }
  int q0 = qt * 64;
  int kb0 = c * 512;
  int len = min(512, q0 + 64 - kb0);
  int ntiles = len >> 5;

  const short* kp = kG + (size_t)b * SEQ * HEAD;
  const short* vp = vG + (size_t)b * SEQ * HEAD;
  int cc0 = tid, cc1 = tid + 256;

  bf16x8 qf[4];
  const short* qrow = q + (size_t)(b * SEQ + q0 + w * 16 + sub) * HEAD + quad * 8;
#pragma unroll
  for (int kc = 0; kc < 4; kc++) qf[kc] = *(const bf16x8*)(qrow + kc * 32);

  f32x4 o[8];
#pragma unroll
  for (int h = 0; h < 8; h++) o[h] = (f32x4)(0.0f);
  float l[4] = {0.0f, 0.0f, 0.0f, 0.0f};
  int wrow = q0 + w * 16;
  int qrq = wrow + quad * 4;

  // prologue staging for tile 0 (linear 8 KB per matrix)
  {
    size_t blk = (size_t)(kb0 >> 5) * 4096;
    async_copy16(kp + blk + cc0 * 8, &Kb[0][cc0 * 8]);
    async_copy16(kp + blk + cc1 * 8, &Kb[0][cc1 * 8]);
    async_copy16(vp + blk + cc0 * 8, &Vb[0][cc0 * 8]);
    async_copy16(vp + blk + cc1 * 8, &Vb[0][cc1 * 8]);
  }

  for (int j = 0; j < ntiles; j++) {
    int kb = kb0 + j * 32;
    int cur = j & 1;
    __syncthreads();  // tile j staged; prior tile's LDS reads consumed
    if (j + 1 < ntiles) {
      int nxt = cur ^ 1;
      size_t blk = (size_t)((kb + 32) >> 5) * 4096;
      async_copy16(kp + blk + cc0 * 8, &Kb[nxt][cc0 * 8]);
      async_copy16(kp + blk + cc1 * 8, &Kb[nxt][cc1 * 8]);
      async_copy16(vp + blk + cc0 * 8, &Vb[nxt][cc0 * 8]);
      async_copy16(vp + blk + cc1 * 8, &Vb[nxt][cc1 * 8]);
    }
    // QK^T: S[16q][32keys]
    f32x4 s0 = (f32x4)(0.0f), s1 = (f32x4)(0.0f);
#pragma unroll
    for (int kk = 0; kk < 4; kk++) {
      bf16x8 f0 = *(const bf16x8*)&Kb[cur][((kk * 4 + quad) * 32 + sub) * 8];
      bf16x8 f1 = *(const bf16x8*)&Kb[cur][((kk * 4 + quad) * 32 + 16 + sub) * 8];
      s0 = __builtin_amdgcn_mfma_f32_16x16x32_bf16(qf[kk], f0, s0, 0, 0, 0);
      s1 = __builtin_amdgcn_mfma_f32_16x16x32_bf16(qf[kk], f1, s1, 0, 0, 0);
    }
    bool edge = (kb + 31 > wrow);
    float e0[4], e1[4];
#pragma unroll
    for (int r = 0; r < 4; r++) {
      e0[r] = __builtin_amdgcn_exp2f(s0[r]);
      e1[r] = __builtin_amdgcn_exp2f(s1[r]);
    }
    if (edge) {
#pragma unroll
      for (int r = 0; r < 4; r++) {
        if (kb + sub > qrq + r) e0[r] = 0.0f;
        if (kb + 16 + sub > qrq + r) e1[r] = 0.0f;
      }
    }
    short* pw = &Pb[w][0];
#pragma unroll
    for (int r = 0; r < 4; r++) {
      l[r] += e0[r] + e1[r];
      pw[(quad * 4 + r) * 40 + sub] = f2bf(e0[r]);
      pw[(quad * 4 + r) * 40 + sub + 16] = f2bf(e1[r]);
    }
    bf16x8 pa = *(const bf16x8*)&pw[sub * 40 + quad * 8];
#pragma unroll
    for (int h8 = 0; h8 < 8; h8++) {
      bf16x8 vf = *(const bf16x8*)&Vb[cur][(quad * 128 + h8 * 16 + sub) * 8];
      o[h8] = __builtin_amdgcn_mfma_f32_16x16x32_bf16(pa, vf, o[h8], 0, 0, 0);
    }
  }

  float* ob = o_acc + (size_t)(b * SEQ + qrq) * HEAD + sub;
#pragma unroll
  for (int r = 0; r < 4; r++)
#pragma unroll
    for (int h8 = 0; h8 < 8; h8++)
      unsafeAtomicAdd(ob + (size_t)r * HEAD + h8 * 16, o[h8][r]);
#pragma unroll
  for (int r = 0; r < 4; r++) {
#pragma unroll
    for (int off = 1; off < 16; off <<= 1) l[r] += __shfl_xor(l[r], off);
  }
  if (sub == 0) {
#pragma unroll
    for (int r = 0; r < 4; r++)
      unsafeAtomicAdd(&l_acc[b * SEQ + qrq + r], l[r]);
  }
}

// ---------------------------------------------------------------------------
// Kernel 3: normalize in place: out[row][:] /= l[row]
// ---------------------------------------------------------------------------
__global__ __launch_bounds__(256) void norm_kernel(
    float* __restrict__ o, const float* __restrict__ l_acc) {
  int idx = blockIdx.x * 256 + threadIdx.x;  // f32x4 groups; 32 per row
  f32x4 v = ((const f32x4*)o)[idx];
  float inv = 1.0f / l_acc[idx >> 5];
  v[0] *= inv; v[1] *= inv; v[2] *= inv; v[3] *= inv;
  ((f32x4*)o)[idx] = v;
}

extern "C" void kernel_launch(void* const* d_in, const int* in_sizes, int n_in,
                              void* d_out, int out_size, void* d_ws, size_t ws_size,
                              hipStream_t stream) {
  const float* x  = (const float*)d_in[0];
  const float* Wk = (const float*)d_in[1];
  const float* Wq = (const float*)d_in[2];
  const float* Wv = (const float*)d_in[3];
  char* ws = (char*)d_ws;
  short* WT3   = (short*)(ws);                           // 768 KiB
  short* vG    = (short*)(ws + (size_t)1  * (1 << 20));  // 4 MiB
  short* q     = (short*)(ws + (size_t)5  * (1 << 20));  // 4 MiB
  short* kG    = (short*)(ws + (size_t)9  * (1 << 20));  // 4 MiB
  float* l_acc = (float*)(ws + (size_t)13 * (1 << 20));  // 64 KiB
  float* out   = (float*)d_out;                          // also o accumulator

  hipMemsetAsync(out, 0, (size_t)BATCH * SEQ * HEAD * sizeof(float), stream);
  hipMemsetAsync(l_acc, 0, (size_t)BATCH * SEQ * sizeof(float), stream);
  wtrans_kernel<<<dim3(128), 384, 0, stream>>>(Wq, Wk, Wv, WT3);
  proj_kernel<<<dim3(768), 256, 0, stream>>>(x, WT3, q, kG, vG);
  attn_kernel<<<dim3(640), 256, 0, stream>>>(q, kG, vG, out, l_acc);
  norm_kernel<<<dim3(2048), 256, 0, stream>>>(out, l_acc);
}

// Round 12
// 153.937 us; speedup vs baseline: 1.0469x; 1.0469x over previous
//
#include <hip/hip_runtime.h>
#include <math.h>

typedef short bf16x2 __attribute__((ext_vector_type(2)));
typedef short bf16x4 __attribute__((ext_vector_type(4)));
typedef short bf16x8 __attribute__((ext_vector_type(8)));
typedef float f32x4 __attribute__((ext_vector_type(4)));

#define EMBED 1024
#define HEAD 128
#define BATCH 8
#define SEQ 2048

__device__ __forceinline__ short f2bf(float f) {
  union { float f; unsigned u; } v;
  v.f = f;
  unsigned r = v.u + 0x7fffu + ((v.u >> 16) & 1u);
  return (short)(r >> 16);
}

__device__ __forceinline__ void async_copy16(const void* g, void* l) {
#if __has_builtin(__builtin_amdgcn_global_load_lds)
  __builtin_amdgcn_global_load_lds(
      (const __attribute__((address_space(1))) unsigned int*)g,
      (__attribute__((address_space(3))) unsigned int*)l, 16, 0, 0);
#else
  *(f32x4*)l = *(const f32x4*)g;
#endif
}

// ---------------------------------------------------------------------------
// Kernel 0: weights fp32 [1024][128] -> WT3 chunk-linear image:
// WT3[(k>>3)*3072 + n*8 + (k&7)], n = mtx*128 + h (q|k|v). Wq * log2e/32.
// ---------------------------------------------------------------------------
__global__ __launch_bounds__(384) void wtrans_kernel(
    const float* __restrict__ Wq, const float* __restrict__ Wk,
    const float* __restrict__ Wv, short* __restrict__ WT3) {
  int kc8 = blockIdx.x;   // 0..127: chunk of 8 consecutive k
  int n = threadIdx.x;    // 0..383
  int mtx = n >> 7, h = n & 127;
  const float* W = (mtx == 0) ? Wq : ((mtx == 1) ? Wk : Wv);
  float scale = (mtx == 0) ? (1.4426950408889634f / 32.0f) : 1.0f;
  bf16x8 o;
#pragma unroll
  for (int j = 0; j < 8; j++)
    o[j] = f2bf(W[(size_t)(kc8 * 8 + j) * HEAD + h] * scale);
  *(bf16x8*)&WT3[(size_t)kc8 * 3072 + n * 8] = o;
}

// ---------------------------------------------------------------------------
// Kernel 1: FUSED QKV projection (R8 structure — the measured best at
// 154.09 us). Block = 64 rows x 192 cols, 256 thr = 4 waves of 64m x 48n,
// BK=64, 16 iters, register-B double-banked from L2-resident WT3. Grid 512
// = 256 mt x 2 nh (XCD-paired; 2 barrier domains/CU — R8's confirmed win;
// 3 domains regressed in R11 via L2 thrash). __syncthreads per iter.
// Epilogue: q row-major / kG chunked / vG chunked.
// ---------------------------------------------------------------------------
#define MFMA_BF16(D, A, B) D = __builtin_amdgcn_mfma_f32_16x16x32_bf16(A, B, D, 0, 0, 0)

#define PROJ_BODY(IT, C0, C1, C2, C3, C4, C5, N0, N1, N2, N3, N4, N5)          \
  {                                                                            \
    int it_ = (IT);                                                            \
    __syncthreads();                                                           \
    if (it_ < 15) {                                                            \
      const short* bp_ = bptr + (it_ + 1) * 24576;                             \
      N0 = *(const bf16x8*)(bp_);                                              \
      N1 = *(const bf16x8*)(bp_ + 128);                                        \
      N2 = *(const bf16x8*)(bp_ + 256);                                        \
      N3 = *(const bf16x8*)(bp_ + 12288);                                      \
      N4 = *(const bf16x8*)(bp_ + 12288 + 128);                                \
      N5 = *(const bf16x8*)(bp_ + 12288 + 256);                                \
      bf16x8 w0_, w1_;                                                         \
      w0_[0] = f2bf(xr0[0]); w0_[1] = f2bf(xr0[1]);                            \
      w0_[2] = f2bf(xr0[2]); w0_[3] = f2bf(xr0[3]);                            \
      w0_[4] = f2bf(xr1[0]); w0_[5] = f2bf(xr1[1]);                            \
      w0_[6] = f2bf(xr1[2]); w0_[7] = f2bf(xr1[3]);                            \
      w1_[0] = f2bf(xr2[0]); w1_[1] = f2bf(xr2[1]);                            \
      w1_[2] = f2bf(xr2[2]); w1_[3] = f2bf(xr2[3]);                            \
      w1_[4] = f2bf(xr3[0]); w1_[5] = f2bf(xr3[1]);                            \
      w1_[6] = f2bf(xr3[2]); w1_[7] = f2bf(xr3[3]);                            \
      *(bf16x8*)&As[(it_ & 1) ^ 1][aoff] = w0_;                                \
      *(bf16x8*)&As[(it_ & 1) ^ 1][aoff + 8] = w1_;                            \
      if (it_ < 14) {                                                          \
        const float* xp_ = xbase + (it_ + 2) * 64;                             \
        xr0 = *(const f32x4*)(xp_);                                            \
        xr1 = *(const f32x4*)(xp_ + 4);                                        \
        xr2 = *(const f32x4*)(xp_ + 8);                                        \
        xr3 = *(const f32x4*)(xp_ + 12);                                       \
      }                                                                        \
    }                                                                          \
    {                                                                          \
      const short* as_ = &As[it_ & 1][0];                                      \
      bf16x8 a0_ = *(const bf16x8*)&as_[sub * 72 + quad * 8];                  \
      bf16x8 a1_ = *(const bf16x8*)&as_[(16 + sub) * 72 + quad * 8];           \
      bf16x8 a2_ = *(const bf16x8*)&as_[(32 + sub) * 72 + quad * 8];           \
      bf16x8 a3_ = *(const bf16x8*)&as_[(48 + sub) * 72 + quad * 8];           \
      MFMA_BF16(acc[0][0], a0_, C0); MFMA_BF16(acc[1][0], a1_, C0);            \
      MFMA_BF16(acc[2][0], a2_, C0); MFMA_BF16(acc[3][0], a3_, C0);            \
      MFMA_BF16(acc[0][1], a0_, C1); MFMA_BF16(acc[1][1], a1_, C1);            \
      MFMA_BF16(acc[2][1], a2_, C1); MFMA_BF16(acc[3][1], a3_, C1);            \
      MFMA_BF16(acc[0][2], a0_, C2); MFMA_BF16(acc[1][2], a1_, C2);            \
      MFMA_BF16(acc[2][2], a2_, C2); MFMA_BF16(acc[3][2], a3_, C2);            \
      a0_ = *(const bf16x8*)&as_[sub * 72 + 32 + quad * 8];                    \
      a1_ = *(const bf16x8*)&as_[(16 + sub) * 72 + 32 + quad * 8];             \
      a2_ = *(const bf16x8*)&as_[(32 + sub) * 72 + 32 + quad * 8];             \
      a3_ = *(const bf16x8*)&as_[(48 + sub) * 72 + 32 + quad * 8];             \
      MFMA_BF16(acc[0][0], a0_, C3); MFMA_BF16(acc[1][0], a1_, C3);            \
      MFMA_BF16(acc[2][0], a2_, C3); MFMA_BF16(acc[3][0], a3_, C3);            \
      MFMA_BF16(acc[0][1], a0_, C4); MFMA_BF16(acc[1][1], a1_, C4);            \
      MFMA_BF16(acc[2][1], a2_, C4); MFMA_BF16(acc[3][1], a3_, C4);            \
      MFMA_BF16(acc[0][2], a0_, C5); MFMA_BF16(acc[1][2], a1_, C5);            \
      MFMA_BF16(acc[2][2], a2_, C5); MFMA_BF16(acc[3][2], a3_, C5);            \
    }                                                                          \
  }

__global__ __launch_bounds__(256, 2) void proj_kernel(
    const float* __restrict__ x, const short* __restrict__ WT3,
    short* __restrict__ q, short* __restrict__ kG, short* __restrict__ vG) {
  __shared__ __align__(16) short As[2][64 * 72];   // 18.4 KiB, stride 144B
  int tid = threadIdx.x;
  int w = tid >> 6, lane = tid & 63, quad = lane >> 4, sub = lane & 15;
  int bx = blockIdx.x;
  int mt = bx & 255;          // both nh of a tile: same XCD (256%8==0)
  int nh = bx >> 8;           // n-half: cols nh*192 .. +192
  int m0 = mt * 64;

  // A staging: thread covers row (tid>>2), 16 k-floats at (tid&3)*16
  int arow = tid >> 2;
  int akq = (tid & 3) * 16;
  const float* xbase = x + (size_t)(m0 + arow) * EMBED + akq;
  int aoff = arow * 72 + akq;

  // per-lane B base: frag(ks,an) at bptr + it*24576 + ks*12288 + an*128
  const short* bptr = WT3 + quad * 3072 + (nh * 192 + w * 48 + sub) * 8;

  f32x4 acc[4][3];
#pragma unroll
  for (int am = 0; am < 4; am++)
#pragma unroll
    for (int an = 0; an < 3; an++) acc[am][an] = (f32x4)(0.0f);

  // prologue: stage A iter 0, prefetch xr for iter 1, load B bank for iter 0
  {
    f32x4 x0 = *(const f32x4*)(xbase + 0);
    f32x4 x1 = *(const f32x4*)(xbase + 4);
    f32x4 x2 = *(const f32x4*)(xbase + 8);
    f32x4 x3 = *(const f32x4*)(xbase + 12);
    bf16x8 w0, w1;
    w0[0]=f2bf(x0[0]); w0[1]=f2bf(x0[1]); w0[2]=f2bf(x0[2]); w0[3]=f2bf(x0[3]);
    w0[4]=f2bf(x1[0]); w0[5]=f2bf(x1[1]); w0[6]=f2bf(x1[2]); w0[7]=f2bf(x1[3]);
    w1[0]=f2bf(x2[0]); w1[1]=f2bf(x2[1]); w1[2]=f2bf(x2[2]); w1[3]=f2bf(x2[3]);
    w1[4]=f2bf(x3[0]); w1[5]=f2bf(x3[1]); w1[6]=f2bf(x3[2]); w1[7]=f2bf(x3[3]);
    *(bf16x8*)&As[0][aoff] = w0;
    *(bf16x8*)&As[0][aoff + 8] = w1;
  }
  f32x4 xr0 = *(const f32x4*)(xbase + 64);
  f32x4 xr1 = *(const f32x4*)(xbase + 68);
  f32x4 xr2 = *(const f32x4*)(xbase + 72);
  f32x4 xr3 = *(const f32x4*)(xbase + 76);
  bf16x8 bA0, bA1, bA2, bA3, bA4, bA5;
  bf16x8 bB0, bB1, bB2, bB3, bB4, bB5;
  bA0 = *(const bf16x8*)(bptr);
  bA1 = *(const bf16x8*)(bptr + 128);
  bA2 = *(const bf16x8*)(bptr + 256);
  bA3 = *(const bf16x8*)(bptr + 12288);
  bA4 = *(const bf16x8*)(bptr + 12288 + 128);
  bA5 = *(const bf16x8*)(bptr + 12288 + 256);

  for (int it2 = 0; it2 < 16; it2 += 2) {
    PROJ_BODY(it2,     bA0, bA1, bA2, bA3, bA4, bA5, bB0, bB1, bB2, bB3, bB4, bB5);
    PROJ_BODY(it2 + 1, bB0, bB1, bB2, bB3, bB4, bB5, bA0, bA1, bA2, bA3, bA4, bA5);
  }

  // epilogue: global frag group G = nh*12 + w*3 + an (16 cols each,
  // 8 per matrix); wave-uniform branch (nh,w uniform, an unrolled).
#pragma unroll
  for (int am = 0; am < 4; am++)
#pragma unroll
    for (int an = 0; an < 3; an++) {
      int g = nh * 12 + w * 3 + an;
      int hcol = (g & 7) * 16 + sub;
      if (g < 8) {                // q: row-major [t][h]
#pragma unroll
        for (int r = 0; r < 4; r++) {
          int m = m0 + am * 16 + quad * 4 + r;
          q[(size_t)m * HEAD + hcol] = f2bf(acc[am][an][r]);
        }
      } else if (g < 16) {        // kG: [t32][h>>3][t&31][h&7]
        size_t base = (size_t)(mt * 2 + (am >> 1)) * 4096 + (hcol >> 3) * 256 + (hcol & 7);
#pragma unroll
        for (int r = 0; r < 4; r++)
          kG[base + ((am & 1) * 16 + quad * 4 + r) * 8] = f2bf(acc[am][an][r]);
      } else {                    // vG: [t32][(t&31)>>3][h][t&7]
        bf16x4 pv;
#pragma unroll
        for (int r = 0; r < 4; r++) pv[r] = f2bf(acc[am][an][r]);
        *(bf16x4*)&vG[(size_t)(mt * 2 + (am >> 1)) * 4096 +
                      ((am & 1) * 2 + (quad >> 1)) * 1024 +
                      hcol * 8 + (quad & 1) * 4] = pv;
      }
    }
}

// ---------------------------------------------------------------------------
// Kernel 2: causal attention flash (R5/R8 structure: double-buffered K/V via
// linear gload_lds from pre-chunked kG/vG, __syncthreads per 32-key tile,
// Pb single-buffered -> 37 KB -> 4 blocks/CU).
// ---------------------------------------------------------------------------
__global__ __launch_bounds__(256, 4) void attn_kernel(
    const short* __restrict__ q, const short* __restrict__ kG,
    const short* __restrict__ vG, float* __restrict__ o_acc,
    float* __restrict__ l_acc) {
  __shared__ __align__(16) short Kb[2][4096];   // [hc 0..15][key 0..31] chunks
  __shared__ __align__(16) short Vb[2][4096];   // [kc 0..3][h 0..127] chunks
  __shared__ __align__(16) short Pb[4][16 * 40];
  int tid = threadIdx.x;
  int w = tid >> 6, lane = tid & 63, quad = lane >> 4, sub = lane & 15;
  int bx = blockIdx.x;
  int b = bx & 7;           // batch <-> XCD affinity (K/V L2-resident)
  int v = 79 - (bx >> 3);   // heavy chunks dispatched first
  int qt, c;
  if (v < 8)       { qt = v;                               c = 0; }
  else if (v < 24) { int i2 = v - 8;  qt = 8  + (i2 >> 1); c = i2 & 1; }
  else if (v < 48) { int i2 = v - 24; qt = 16 + i2 / 3;    c = i2 % 3; }
  else             { int i2 = v - 48; qt = 24 + (i2 >> 2); c = i2 & 3; }
  int q0 = qt * 64;
  int kb0 = c * 512;
  int len = min(512, q0 + 64 - kb0);
  int ntiles = len >> 5;

  const short* kp = kG + (size_t)b * SEQ * HEAD;
  const short* vp = vG + (size_t)b * SEQ * HEAD;
  int cc0 = tid, cc1 = tid + 256;

  bf16x8 qf[4];
  const short* qrow = q + (size_t)(b * SEQ + q0 + w * 16 + sub) * HEAD + quad * 8;
#pragma unroll
  for (int kc = 0; kc < 4; kc++) qf[kc] = *(const bf16x8*)(qrow + kc * 32);

  f32x4 o[8];
#pragma unroll
  for (int h = 0; h < 8; h++) o[h] = (f32x4)(0.0f);
  float l[4] = {0.0f, 0.0f, 0.0f, 0.0f};
  int wrow = q0 + w * 16;
  int qrq = wrow + quad * 4;

  // prologue staging for tile 0 (linear 8 KB per matrix)
  {
    size_t blk = (size_t)(kb0 >> 5) * 4096;
    async_copy16(kp + blk + cc0 * 8, &Kb[0][cc0 * 8]);
    async_copy16(kp + blk + cc1 * 8, &Kb[0][cc1 * 8]);
    async_copy16(vp + blk + cc0 * 8, &Vb[0][cc0 * 8]);
    async_copy16(vp + blk + cc1 * 8, &Vb[0][cc1 * 8]);
  }

  for (int j = 0; j < ntiles; j++) {
    int kb = kb0 + j * 32;
    int cur = j & 1;
    __syncthreads();  // tile j staged; prior tile's LDS reads consumed
    if (j + 1 < ntiles) {
      int nxt = cur ^ 1;
      size_t blk = (size_t)((kb + 32) >> 5) * 4096;
      async_copy16(kp + blk + cc0 * 8, &Kb[nxt][cc0 * 8]);
      async_copy16(kp + blk + cc1 * 8, &Kb[nxt][cc1 * 8]);
      async_copy16(vp + blk + cc0 * 8, &Vb[nxt][cc0 * 8]);
      async_copy16(vp + blk + cc1 * 8, &Vb[nxt][cc1 * 8]);
    }
    // QK^T: S[16q][32keys]
    f32x4 s0 = (f32x4)(0.0f), s1 = (f32x4)(0.0f);
#pragma unroll
    for (int kk = 0; kk < 4; kk++) {
      bf16x8 f0 = *(const bf16x8*)&Kb[cur][((kk * 4 + quad) * 32 + sub) * 8];
      bf16x8 f1 = *(const bf16x8*)&Kb[cur][((kk * 4 + quad) * 32 + 16 + sub) * 8];
      s0 = __builtin_amdgcn_mfma_f32_16x16x32_bf16(qf[kk], f0, s0, 0, 0, 0);
      s1 = __builtin_amdgcn_mfma_f32_16x16x32_bf16(qf[kk], f1, s1, 0, 0, 0);
    }
    bool edge = (kb + 31 > wrow);
    float e0[4], e1[4];
#pragma unroll
    for (int r = 0; r < 4; r++) {
      e0[r] = __builtin_amdgcn_exp2f(s0[r]);
      e1[r] = __builtin_amdgcn_exp2f(s1[r]);
    }
    if (edge) {
#pragma unroll
      for (int r = 0; r < 4; r++) {
        if (kb + sub > qrq + r) e0[r] = 0.0f;
        if (kb + 16 + sub > qrq + r) e1[r] = 0.0f;
      }
    }
    short* pw = &Pb[w][0];
#pragma unroll
    for (int r = 0; r < 4; r++) {
      l[r] += e0[r] + e1[r];
      pw[(quad * 4 + r) * 40 + sub] = f2bf(e0[r]);
      pw[(quad * 4 + r) * 40 + sub + 16] = f2bf(e1[r]);
    }
    bf16x8 pa = *(const bf16x8*)&pw[sub * 40 + quad * 8];
#pragma unroll
    for (int h8 = 0; h8 < 8; h8++) {
      bf16x8 vf = *(const bf16x8*)&Vb[cur][(quad * 128 + h8 * 16 + sub) * 8];
      o[h8] = __builtin_amdgcn_mfma_f32_16x16x32_bf16(pa, vf, o[h8], 0, 0, 0);
    }
  }

  float* ob = o_acc + (size_t)(b * SEQ + qrq) * HEAD + sub;
#pragma unroll
  for (int r = 0; r < 4; r++)
#pragma unroll
    for (int h8 = 0; h8 < 8; h8++)
      unsafeAtomicAdd(ob + (size_t)r * HEAD + h8 * 16, o[h8][r]);
#pragma unroll
  for (int r = 0; r < 4; r++) {
#pragma unroll
    for (int off = 1; off < 16; off <<= 1) l[r] += __shfl_xor(l[r], off);
  }
  if (sub == 0) {
#pragma unroll
    for (int r = 0; r < 4; r++)
      unsafeAtomicAdd(&l_acc[b * SEQ + qrq + r], l[r]);
  }
}

// ---------------------------------------------------------------------------
// Kernel 3: normalize in place: out[row][:] /= l[row]
// ---------------------------------------------------------------------------
__global__ __launch_bounds__(256) void norm_kernel(
    float* __restrict__ o, const float* __restrict__ l_acc) {
  int idx = blockIdx.x * 256 + threadIdx.x;  // f32x4 groups; 32 per row
  f32x4 v = ((const f32x4*)o)[idx];
  float inv = 1.0f / l_acc[idx >> 5];
  v[0] *= inv; v[1] *= inv; v[2] *= inv; v[3] *= inv;
  ((f32x4*)o)[idx] = v;
}

extern "C" void kernel_launch(void* const* d_in, const int* in_sizes, int n_in,
                              void* d_out, int out_size, void* d_ws, size_t ws_size,
                              hipStream_t stream) {
  const float* x  = (const float*)d_in[0];
  const float* Wk = (const float*)d_in[1];
  const float* Wq = (const float*)d_in[2];
  const float* Wv = (const float*)d_in[3];
  char* ws = (char*)d_ws;
  short* WT3   = (short*)(ws);                           // 768 KiB
  short* vG    = (short*)(ws + (size_t)1  * (1 << 20));  // 4 MiB
  short* q     = (short*)(ws + (size_t)5  * (1 << 20));  // 4 MiB
  short* kG    = (short*)(ws + (size_t)9  * (1 << 20));  // 4 MiB
  float* l_acc = (float*)(ws + (size_t)13 * (1 << 20));  // 64 KiB
  float* out   = (float*)d_out;                          // also o accumulator

  hipMemsetAsync(out, 0, (size_t)BATCH * SEQ * HEAD * sizeof(float), stream);
  hipMemsetAsync(l_acc, 0, (size_t)BATCH * SEQ * sizeof(float), stream);
  wtrans_kernel<<<dim3(128), 384, 0, stream>>>(Wq, Wk, Wv, WT3);
  proj_kernel<<<dim3(512), 256, 0, stream>>>(x, WT3, q, kG, vG);
  attn_kernel<<<dim3(640), 256, 0, stream>>>(q, kG, vG, out, l_acc);
  norm_kernel<<<dim3(2048), 256, 0, stream>>>(out, l_acc);
}